// Round 1
// baseline (580.491 us; speedup 1.0000x reference)
//
#include <hip/hip_runtime.h>

// z <- tanh(z @ W^T + x), 50 fixed-point iterations. B=16384, D=512.
// Persistent-block design: each block owns 64 rows of z, kept in LDS (bf16)
// across all iterations. W is pre-converted to bf16 in MFMA A-fragment order
// (512 KB in d_ws, L2-resident). MFMA 32x32x16 bf16, fp32 accumulate.

typedef short s8v  __attribute__((ext_vector_type(8)));   // 8 bf16 = 4 VGPRs
typedef float f32x16 __attribute__((ext_vector_type(16)));

#define BATCH 16384
#define DIM   512
#define TM    64        // rows per block
#define NITER 50        // total iterations (1 init + 49 GEMM)

__device__ __forceinline__ unsigned short f2bf(float f) {
    unsigned int u = __float_as_uint(f);
    u += 0x7fffu + ((u >> 16) & 1u);          // round-to-nearest-even
    return (unsigned short)(u >> 16);
}

__device__ __forceinline__ float fast_tanh(float v) {
    // tanh(v) = (e^{2v}-1)/(e^{2v}+1); clamp keeps exp finite, tanh(±10)==±1 in fp32
    v = fminf(10.0f, fmaxf(-10.0f, v));
    float t = __builtin_amdgcn_exp2f(v * 2.8853900817779268f);  // 2*log2(e)
    return (t - 1.0f) * __builtin_amdgcn_rcpf(t + 1.0f);
}

__device__ __forceinline__ f32x16 zero16() {
    f32x16 v;
#pragma unroll
    for (int i = 0; i < 16; ++i) v[i] = 0.0f;
    return v;
}

// Convert W (fp32 [512][512], row-major) into bf16 A-fragments for
// v_mfma_f32_32x32x16_bf16. Fragment granule tid = (jt*32 + ks)*64 + lane,
// holding W[j = 32*jt + (lane&31)][k = 16*ks + 8*(lane>>5) .. +8] as 16 B.
__global__ void wprep_kernel(const float* __restrict__ W, unsigned short* __restrict__ Wf) {
    int tid = blockIdx.x * blockDim.x + threadIdx.x;   // 0..32767
    int jt  = tid >> 11;          // / 2048
    int rem = tid & 2047;
    int ks  = rem >> 6;
    int L   = rem & 63;
    int j   = jt * 32 + (L & 31);
    int k   = ks * 16 + (L >> 5) * 8;
    const float* src = W + j * DIM + k;
    uint4 p;
    p.x = (unsigned)f2bf(src[0]) | ((unsigned)f2bf(src[1]) << 16);
    p.y = (unsigned)f2bf(src[2]) | ((unsigned)f2bf(src[3]) << 16);
    p.z = (unsigned)f2bf(src[4]) | ((unsigned)f2bf(src[5]) << 16);
    p.w = (unsigned)f2bf(src[6]) | ((unsigned)f2bf(src[7]) << 16);
    ((uint4*)Wf)[tid] = p;
}

// LDS z layout: row r (64 rows) x 512 bf16, stored as 64 chunks of 16 B per
// row with XOR swizzle chunk' = chunk ^ (r & 7)  -> conflict-free ds_read_b128
// across 32 consecutive-row lanes (stride would otherwise alias all lanes to
// one bank group).
__device__ __forceinline__ int z_addr(int r, int j) {   // element index into zt[]
    int c  = j >> 3;
    int lo = j & 7;
    return r * DIM + (((c ^ (r & 7)) << 3) | lo);
}

__global__ __launch_bounds__(512, 2)
void fixpoint_kernel(const float* __restrict__ x,
                     const unsigned short* __restrict__ Wf,
                     float* __restrict__ out) {
    __shared__ alignas(16) unsigned short zt[TM * DIM];   // 64 KB

    const int tid  = threadIdx.x;
    const int lane = tid & 63;
    const int w    = tid >> 6;       // wave 0..7, owns j-slab [64w, 64w+64)
    const int l31  = lane & 31;
    const int h    = lane >> 5;      // k-half for A/B fragments
    const int r0   = blockIdx.x * TM;
    const int jt0  = 2 * w;          // first 32-wide j-tile of this wave

    // ---- iteration 1: z = tanh(x) ----
    for (int idx = tid; idx < TM * DIM; idx += 512) {
        int r = idx >> 9, j = idx & (DIM - 1);
        zt[z_addr(r, j)] = f2bf(fast_tanh(x[(size_t)(r0 + r) * DIM + j]));
    }
    __syncthreads();

    const s8v* Wfv = (const s8v*)Wf;
    const int swz = l31 & 7;   // row-swizzle key (same for r and r+32)

    for (int it = 0; it < NITER - 1; ++it) {
        f32x16 acc00 = zero16(), acc01 = zero16(), acc10 = zero16(), acc11 = zero16();

#pragma unroll 4
        for (int ks = 0; ks < 32; ++ks) {
            // A fragments: W rows [64w,64w+64), contiguous 1024 B per wave-load
            s8v a0 = Wfv[(jt0 * 32 + ks) * 64 + lane];
            s8v a1 = Wfv[((jt0 + 1) * 32 + ks) * 64 + lane];
            // B fragments: z rows l31 / l31+32, k = 16*ks + 8*h .. +8
            int c = ((2 * ks + h) ^ swz) << 3;
            s8v b0 = *(const s8v*)&zt[l31 * DIM + c];
            s8v b1 = *(const s8v*)&zt[(l31 + 32) * DIM + c];
            acc00 = __builtin_amdgcn_mfma_f32_32x32x16_bf16(a0, b0, acc00, 0, 0, 0);
            acc01 = __builtin_amdgcn_mfma_f32_32x32x16_bf16(a0, b1, acc01, 0, 0, 0);
            acc10 = __builtin_amdgcn_mfma_f32_32x32x16_bf16(a1, b0, acc10, 0, 0, 0);
            acc11 = __builtin_amdgcn_mfma_f32_32x32x16_bf16(a1, b1, acc11, 0, 0, 0);
        }
        __syncthreads();   // all waves done reading zt

        const bool last = (it == NITER - 2);

        // D[m=j][n=r]: col = lane&31 -> z-row; row = (reg&3)+8*(reg>>2)+4*h -> j
        auto epi = [&](const f32x16& acc, int jb, int rl) {
            const size_t rowoff = (size_t)(r0 + rl) * DIM;
#pragma unroll
            for (int g = 0; g < 4; ++g) {
                int j0 = jb + 8 * g + 4 * h;
                const float4 xv = *(const float4*)&x[rowoff + j0];
                float v0 = fast_tanh(acc[4 * g + 0] + xv.x);
                float v1 = fast_tanh(acc[4 * g + 1] + xv.y);
                float v2 = fast_tanh(acc[4 * g + 2] + xv.z);
                float v3 = fast_tanh(acc[4 * g + 3] + xv.w);
                uint2 p;
                p.x = (unsigned)f2bf(v0) | ((unsigned)f2bf(v1) << 16);
                p.y = (unsigned)f2bf(v2) | ((unsigned)f2bf(v3) << 16);
                *(uint2*)&zt[z_addr(rl, j0)] = p;   // j0 % 4 == 0 -> 8B aligned
                if (last) {
                    float4 o; o.x = v0; o.y = v1; o.z = v2; o.w = v3;
                    *(float4*)&out[rowoff + j0] = o;
                }
            }
        };
        epi(acc00, w * 64,      l31);
        epi(acc01, w * 64,      l31 + 32);
        epi(acc10, w * 64 + 32, l31);
        epi(acc11, w * 64 + 32, l31 + 32);
        __syncthreads();   // z_next visible before next iteration reads
    }
}

extern "C" void kernel_launch(void* const* d_in, const int* in_sizes, int n_in,
                              void* d_out, int out_size, void* d_ws, size_t ws_size,
                              hipStream_t stream) {
    const float* x = (const float*)d_in[0];   // [16384, 512] fp32
    const float* W = (const float*)d_in[1];   // [512, 512] fp32
    float* out = (float*)d_out;               // [16384, 512] fp32
    unsigned short* Wf = (unsigned short*)d_ws;   // 512 KB bf16 fragments

    wprep_kernel<<<128, 256, 0, stream>>>(W, Wf);
    fixpoint_kernel<<<BATCH / TM, 512, 0, stream>>>(x, Wf, out);
}